// Round 4
// baseline (1284.724 us; speedup 1.0000x reference)
//
#include <hip/hip_runtime.h>

#define D 64
#define F 128
#define NBMAX 256

typedef unsigned int uint;
typedef unsigned short ushort;
typedef short s16x8 __attribute__((ext_vector_type(8)));
typedef float f32x4 __attribute__((ext_vector_type(4)));

__device__ __forceinline__ float bf16lo(uint u) { return __uint_as_float(u << 16); }
__device__ __forceinline__ float bf16hi(uint u) { return __uint_as_float(u & 0xFFFF0000u); }
__device__ __forceinline__ ushort f2bf16(float f) {
    uint u = __float_as_uint(f);
    u += 0x7FFFu + ((u >> 16) & 1u);   // RNE
    return (ushort)(u >> 16);
}
__device__ __forceinline__ uint pk2bf(float lo, float hi) {
    return (uint)f2bf16(lo) | ((uint)f2bf16(hi) << 16);
}
__device__ __forceinline__ float rdlane(float v, int l) {
    return __uint_as_float(__builtin_amdgcn_readlane(__float_as_uint(v), l));
}

// ================= bucketed CSR build (N <= 65536) =================

__global__ __launch_bounds__(256) void bucket_hist(const int* __restrict__ dst,
                                                   int* __restrict__ gb, int E, int nb) {
    __shared__ int h[NBMAX];
    for (int t = threadIdx.x; t < nb; t += 256) h[t] = 0;
    __syncthreads();
    int start = blockIdx.x * 4096;
    int end   = start + 4096 < E ? start + 4096 : E;
    for (int i = start + threadIdx.x; i < end; i += 256)
        atomicAdd(&h[dst[i] >> 8], 1);
    __syncthreads();
    for (int t = threadIdx.x; t < nb; t += 256)
        if (h[t]) atomicAdd(&gb[t], h[t]);
}

__global__ void bucket_scan(const int* __restrict__ gb, int* __restrict__ gboff,
                            int* __restrict__ gcur, int nb) {
    if (threadIdx.x == 0) {
        int s = 0;
        for (int b = 0; b < nb; ++b) { gboff[b] = s; gcur[b] = s; s += gb[b]; }
        gboff[nb] = s;
    }
}

__global__ __launch_bounds__(256) void bucket_scatter(const int* __restrict__ src,
                                                      const int* __restrict__ dst,
                                                      int* __restrict__ gcur,
                                                      int* __restrict__ packed, int E, int nb) {
    __shared__ int h[NBMAX], base[NBMAX], lcur[NBMAX];
    for (int t = threadIdx.x; t < nb; t += 256) h[t] = 0;
    __syncthreads();
    int start = blockIdx.x * 4096;
    int end   = start + 4096 < E ? start + 4096 : E;
    for (int i = start + threadIdx.x; i < end; i += 256)
        atomicAdd(&h[dst[i] >> 8], 1);
    __syncthreads();
    for (int t = threadIdx.x; t < nb; t += 256) {
        base[t] = h[t] ? atomicAdd(&gcur[t], h[t]) : 0;
        lcur[t] = 0;
    }
    __syncthreads();
    for (int i = start + threadIdx.x; i < end; i += 256) {
        int d = dst[i];
        int b = d >> 8;
        int pos = base[b] + atomicAdd(&lcur[b], 1);
        packed[pos] = (src[i] << 8) | (d & 255);
    }
}

__global__ __launch_bounds__(256) void bucket_deg(const int* __restrict__ gboff,
                                                  const int* __restrict__ packed,
                                                  int* __restrict__ deg, int N) {
    __shared__ int h[NBMAX];
    int b = blockIdx.x;
    h[threadIdx.x] = 0;
    __syncthreads();
    int st = gboff[b], en = gboff[b + 1];
    for (int i = st + threadIdx.x; i < en; i += 256)
        atomicAdd(&h[packed[i] & 255], 1);
    __syncthreads();
    int node = (b << 8) + threadIdx.x;
    if (node < N) deg[node] = h[threadIdx.x];
}

__global__ __launch_bounds__(256) void bucket_fill(const int* __restrict__ gboff,
                                                   const int* __restrict__ packed,
                                                   const int* __restrict__ row_ptr,
                                                   int* __restrict__ col, int N) {
    __shared__ int lcur[NBMAX];
    int b = blockIdx.x;
    int node = (b << 8) + threadIdx.x;
    lcur[threadIdx.x] = (node < N) ? row_ptr[node] : 0;
    __syncthreads();
    int st = gboff[b], en = gboff[b + 1];
    for (int i = st + threadIdx.x; i < en; i += 256) {
        int p = packed[i];
        int pos = atomicAdd(&lcur[p & 255], 1);
        col[pos] = p >> 8;
    }
}

// ================= fallback CSR build (N > 65536) =================

__global__ void count_deg_kernel(const int* __restrict__ dst, int* __restrict__ deg, int E) {
    int i = blockIdx.x * blockDim.x + threadIdx.x;
    if (i < E) atomicAdd(&deg[dst[i]], 1);
}

__global__ void fill_kernel(const int* __restrict__ src, const int* __restrict__ dst,
                            int* __restrict__ cursor, int* __restrict__ col, int E) {
    int i = blockIdx.x * blockDim.x + threadIdx.x;
    if (i < E) {
        int d_ = dst[i];
        int pos = atomicAdd(&cursor[d_], 1);
        col[pos] = src[i];
    }
}

// ================= row_ptr scan (deg padded to multiple of 16) =================

__global__ __launch_bounds__(1024) void scan_kernel(const int* __restrict__ deg,
                                                    int* __restrict__ row_ptr, int n) {
    __shared__ int wsum[16];
    int lane = threadIdx.x & 63;
    int wid  = threadIdx.x >> 6;
    int carry = 0;
    const int CH = 4096;
    for (int base = 0; base < n; base += CH) {
        int i0 = base + (int)threadIdx.x * 4;
        int v0 = (i0     < n) ? ((deg[i0]     + 15) & ~15) : 0;
        int v1 = (i0 + 1 < n) ? ((deg[i0 + 1] + 15) & ~15) : 0;
        int v2 = (i0 + 2 < n) ? ((deg[i0 + 2] + 15) & ~15) : 0;
        int v3 = (i0 + 3 < n) ? ((deg[i0 + 3] + 15) & ~15) : 0;
        int p0 = v0, p1 = p0 + v1, p2 = p1 + v2, p3 = p2 + v3;
        int tsum = p3;
        int s = tsum;
        #pragma unroll
        for (int off = 1; off < 64; off <<= 1) {
            int t = __shfl_up(s, off);
            if (lane >= off) s += t;
        }
        if (lane == 63) wsum[wid] = s;
        __syncthreads();
        int wbase = 0, chunk_total = 0;
        #pragma unroll
        for (int w = 0; w < 16; ++w) {
            int t = wsum[w];
            chunk_total += t;
            if (w < wid) wbase += t;
        }
        __syncthreads();
        int ex = carry + wbase + (s - tsum);
        if (i0     < n) row_ptr[i0 + 1] = ex + p0;
        if (i0 + 1 < n) row_ptr[i0 + 2] = ex + p1;
        if (i0 + 2 < n) row_ptr[i0 + 3] = ex + p2;
        if (i0 + 3 < n) row_ptr[i0 + 4] = ex + p3;
        carry += chunk_total;
    }
    if (threadIdx.x == 0) row_ptr[0] = 0;
}

__global__ void pad_kernel(const int* __restrict__ row_ptr, const int* __restrict__ deg,
                           int* __restrict__ col, int N) {
    int v = blockIdx.x * blockDim.x + threadIdx.x;
    if (v < N) {
        int st = row_ptr[v] + deg[v];
        int en = row_ptr[v + 1];
        for (int k = st; k < en; ++k) col[k] = N;  // zero row
    }
}

// ================= Wx via MFMA (bf16 in, f32 acc) + fused emb1 init =================
// A = x tile (16 nodes x 128), B = W1^T (128 x 64). B fragments live in registers.
// Within-lane k-order cancels between A and B fragments; C/D mapping per m89:
// col(lane&15)=out dim, row((lane>>4)*4+reg)=node.

__global__ __launch_bounds__(256) void wx_mfma_kernel(const float* __restrict__ x,
                                                      const float* __restrict__ W1,
                                                      const float* __restrict__ b1,
                                                      const float* __restrict__ b2,
                                                      float* __restrict__ Wx,
                                                      ushort* __restrict__ emb, int N) {
    int lane = threadIdx.x & 63;
    int wv = blockIdx.x * 4 + (threadIdx.x >> 6);
    int nwaves = gridDim.x * 4;
    int r16 = lane & 15;
    int kg  = lane >> 4;

    s16x8 bf[4][4];
    #pragma unroll
    for (int nt = 0; nt < 4; ++nt) {
        const float* wrow = W1 + (size_t)(nt * 16 + r16) * F;
        #pragma unroll
        for (int ks = 0; ks < 4; ++ks) {
            const float4* p = reinterpret_cast<const float4*>(wrow + ks * 32 + kg * 8);
            float4 f0 = p[0], f1 = p[1];
            union { s16x8 v; uint u[4]; } t;
            t.u[0] = pk2bf(f0.x, f0.y); t.u[1] = pk2bf(f0.z, f0.w);
            t.u[2] = pk2bf(f1.x, f1.y); t.u[3] = pk2bf(f1.z, f1.w);
            bf[nt][ks] = t.v;
        }
    }
    float b1v[4], b2v[4];
    #pragma unroll
    for (int nt = 0; nt < 4; ++nt) {
        b1v[nt] = b1[nt * 16 + r16];
        b2v[nt] = b2[nt * 16 + r16];
    }

    int ntiles = (N + 15) >> 4;
    for (int tile = wv; tile < ntiles; tile += nwaves) {
        int row0 = tile << 4;
        int arow = row0 + r16;
        if (arow >= N) arow = N - 1;
        s16x8 af[4];
        #pragma unroll
        for (int ks = 0; ks < 4; ++ks) {
            const float4* p = reinterpret_cast<const float4*>(x + (size_t)arow * F + ks * 32 + kg * 8);
            float4 f0 = p[0], f1 = p[1];
            union { s16x8 v; uint u[4]; } t;
            t.u[0] = pk2bf(f0.x, f0.y); t.u[1] = pk2bf(f0.z, f0.w);
            t.u[2] = pk2bf(f1.x, f1.y); t.u[3] = pk2bf(f1.z, f1.w);
            af[ks] = t.v;
        }
        #pragma unroll
        for (int nt = 0; nt < 4; ++nt) {
            f32x4 acc = {0.f, 0.f, 0.f, 0.f};
            #pragma unroll
            for (int ks = 0; ks < 4; ++ks)
                acc = __builtin_amdgcn_mfma_f32_16x16x32_bf16(af[ks], bf[nt][ks], acc, 0, 0, 0);
            int outd = nt * 16 + r16;
            #pragma unroll
            for (int r = 0; r < 4; ++r) {
                int node = row0 + kg * 4 + r;
                if (node < N) {
                    float wxv = acc[r] + b1v[nt];
                    Wx[(size_t)node * D + outd] = wxv;
                    float e = wxv + b2v[nt];
                    emb[(size_t)node * D + outd] = f2bf16(e > 0.f ? e : 0.f);
                }
            }
        }
    }
}

// ================= fused iteration (bf16 emb), pipelined gathers =================
// lane = 8*g + s: group g covers neighbor slots k+g, k+8+g; lane reads 16B (8 dims).

__global__ __launch_bounds__(256, 8) void step_kernel(const ushort* __restrict__ emb_in,
                                                      ushort* __restrict__ emb_out,
                                                      const float* __restrict__ Wx,
                                                      const float* __restrict__ W2,
                                                      const float* __restrict__ b2,
                                                      const int* __restrict__ row_ptr,
                                                      const int* __restrict__ col, int N) {
    __shared__ float w2t[D][D + 1];  // w2t[k][d] = W2[d][k]; +1 pad -> conflict-free
    int t = threadIdx.x;
    #pragma unroll
    for (int i = t; i < D * D; i += 256) {
        int dd = i >> 6, kk = i & 63;
        w2t[kk][dd] = W2[i];
    }
    __syncthreads();
    int lane = t & 63, wid = t >> 6;
    float b2v = b2[lane];
    int g = lane >> 3, s = lane & 7;
    int nw = gridDim.x * 4;
    for (int v = blockIdx.x * 4 + wid; v < N; v += nw) {
        int st = row_ptr[v], en = row_ptr[v + 1];  // multiple of 16
        float a0 = 0.f, a1 = 0.f, a2 = 0.f, a3 = 0.f, a4 = 0.f, a5 = 0.f, a6 = 0.f, a7 = 0.f;
        if (st < en) {
            int u0 = col[st + g], u1 = col[st + 8 + g];
            uint4 q0 = reinterpret_cast<const uint4*>(emb_in + ((size_t)u0 << 6))[s];
            uint4 q1 = reinterpret_cast<const uint4*>(emb_in + ((size_t)u1 << 6))[s];
            int k = st + 16;
            int n0 = N, n1 = N;
            if (k < en) { n0 = col[k + g]; n1 = col[k + 8 + g]; }
            for (; k < en; k += 16) {
                uint4 p0 = reinterpret_cast<const uint4*>(emb_in + ((size_t)n0 << 6))[s];
                uint4 p1 = reinterpret_cast<const uint4*>(emb_in + ((size_t)n1 << 6))[s];
                int k2 = k + 16;
                int m0 = N, m1 = N;
                if (k2 < en) { m0 = col[k2 + g]; m1 = col[k2 + 8 + g]; }
                a0 += bf16lo(q0.x); a1 += bf16hi(q0.x);
                a2 += bf16lo(q0.y); a3 += bf16hi(q0.y);
                a4 += bf16lo(q0.z); a5 += bf16hi(q0.z);
                a6 += bf16lo(q0.w); a7 += bf16hi(q0.w);
                a0 += bf16lo(q1.x); a1 += bf16hi(q1.x);
                a2 += bf16lo(q1.y); a3 += bf16hi(q1.y);
                a4 += bf16lo(q1.z); a5 += bf16hi(q1.z);
                a6 += bf16lo(q1.w); a7 += bf16hi(q1.w);
                q0 = p0; q1 = p1; n0 = m0; n1 = m1;
            }
            a0 += bf16lo(q0.x); a1 += bf16hi(q0.x);
            a2 += bf16lo(q0.y); a3 += bf16hi(q0.y);
            a4 += bf16lo(q0.z); a5 += bf16hi(q0.z);
            a6 += bf16lo(q0.w); a7 += bf16hi(q0.w);
            a0 += bf16lo(q1.x); a1 += bf16hi(q1.x);
            a2 += bf16lo(q1.y); a3 += bf16hi(q1.y);
            a4 += bf16lo(q1.z); a5 += bf16hi(q1.z);
            a6 += bf16lo(q1.w); a7 += bf16hi(q1.w);
        }
        #pragma unroll
        for (int off = 8; off < 64; off <<= 1) {
            a0 += __shfl_xor(a0, off); a1 += __shfl_xor(a1, off);
            a2 += __shfl_xor(a2, off); a3 += __shfl_xor(a3, off);
            a4 += __shfl_xor(a4, off); a5 += __shfl_xor(a5, off);
            a6 += __shfl_xor(a6, off); a7 += __shfl_xor(a7, off);
        }
        float r = Wx[(size_t)v * D + lane] + b2v;
        #pragma unroll
        for (int kk = 0; kk < D; ++kk) {
            float av;
            switch (kk & 7) {
                case 0: av = rdlane(a0, kk >> 3); break;
                case 1: av = rdlane(a1, kk >> 3); break;
                case 2: av = rdlane(a2, kk >> 3); break;
                case 3: av = rdlane(a3, kk >> 3); break;
                case 4: av = rdlane(a4, kk >> 3); break;
                case 5: av = rdlane(a5, kk >> 3); break;
                case 6: av = rdlane(a6, kk >> 3); break;
                default: av = rdlane(a7, kk >> 3); break;
            }
            r += av * w2t[kk][lane];
        }
        emb_out[(size_t)v * D + lane] = f2bf16(r > 0.f ? r : 0.f);
    }
}

// ================= final: out[d] = sum_v emb[v][d] =================

__global__ __launch_bounds__(256) void reduce_kernel(const ushort* __restrict__ emb,
                                                     float* __restrict__ out, int N) {
    int lane = threadIdx.x & 63;
    int wid  = threadIdx.x >> 6;
    float acc = 0.f;
    int nw = gridDim.x * 4;
    for (int v = blockIdx.x * 4 + wid; v < N; v += nw)
        acc += __uint_as_float((uint)emb[(size_t)v * D + lane] << 16);
    __shared__ float red[256];
    red[threadIdx.x] = acc;
    __syncthreads();
    if (threadIdx.x < 64) {
        float sum = red[threadIdx.x] + red[threadIdx.x + 64] +
                    red[threadIdx.x + 128] + red[threadIdx.x + 192];
        atomicAdd(&out[threadIdx.x], sum);
    }
}

extern "C" void kernel_launch(void* const* d_in, const int* in_sizes, int n_in,
                              void* d_out, int out_size, void* d_ws, size_t ws_size,
                              hipStream_t stream) {
    const float* x    = (const float*)d_in[0];
    const float* W1   = (const float*)d_in[1];
    const float* b1   = (const float*)d_in[2];
    const float* W2   = (const float*)d_in[3];
    const float* b2   = (const float*)d_in[4];
    const int*   esrc = (const int*)d_in[5];
    const int*   edst = (const int*)d_in[6];
    int N = in_sizes[0] / F;
    int E = in_sizes[5];
    float* out = (float*)d_out;

    char* ws = (char*)d_ws;
    size_t off = 0;
    auto alloc = [&](size_t bytes) -> char* {
        char* p = ws + off;
        off += (bytes + 255) & ~(size_t)255;
        return p;
    };
    float*  Wx      = (float*)alloc((size_t)N * D * 4);
    ushort* embA    = (ushort*)alloc(((size_t)N + 1) * D * 2);
    ushort* embB    = (ushort*)alloc(((size_t)N + 1) * D * 2);
    int*    row_ptr = (int*)alloc(((size_t)N + 1) * 4);
    int*    deg     = (int*)alloc((size_t)N * 4);
    int*    col     = (int*)alloc(((size_t)E + 15 * (size_t)N) * 4);
    int*    packed  = (int*)alloc((size_t)E * 4);
    int*    gb      = (int*)alloc((NBMAX + 1) * 4);
    int*    gboff   = (int*)alloc((NBMAX + 1) * 4);
    int*    gcur    = (int*)alloc((NBMAX + 1) * 4);
    int*    cursor  = (int*)alloc((size_t)N * 4);  // fallback path only

    hipMemsetAsync(out, 0, (size_t)out_size * 4, stream);
    hipMemsetAsync(embA + (size_t)N * D, 0, D * 2, stream);
    hipMemsetAsync(embB + (size_t)N * D, 0, D * 2, stream);

    int nb = ((N - 1) >> 8) + 1;
    int nchunks = (E + 4095) / 4096;
    if (N <= 65536) {
        hipMemsetAsync(gb, 0, (size_t)nb * 4, stream);
        bucket_hist<<<nchunks, 256, 0, stream>>>(edst, gb, E, nb);
        bucket_scan<<<1, 64, 0, stream>>>(gb, gboff, gcur, nb);
        bucket_scatter<<<nchunks, 256, 0, stream>>>(esrc, edst, gcur, packed, E, nb);
        bucket_deg<<<nb, 256, 0, stream>>>(gboff, packed, deg, N);
        scan_kernel<<<1, 1024, 0, stream>>>(deg, row_ptr, N);
        bucket_fill<<<nb, 256, 0, stream>>>(gboff, packed, row_ptr, col, N);
    } else {
        hipMemsetAsync(deg, 0, (size_t)N * 4, stream);
        count_deg_kernel<<<(E + 255) / 256, 256, 0, stream>>>(edst, deg, E);
        scan_kernel<<<1, 1024, 0, stream>>>(deg, row_ptr, N);
        hipMemcpyAsync(cursor, row_ptr, (size_t)N * 4, hipMemcpyDeviceToDevice, stream);
        fill_kernel<<<(E + 255) / 256, 256, 0, stream>>>(esrc, edst, cursor, col, E);
    }
    pad_kernel<<<(N + 255) / 256, 256, 0, stream>>>(row_ptr, deg, col, N);

    wx_mfma_kernel<<<256, 256, 0, stream>>>(x, W1, b1, b2, Wx, embA, N);

    ushort* pin = embA;
    ushort* pout = embB;
    for (int t = 1; t < 10; ++t) {
        step_kernel<<<2048, 256, 0, stream>>>(pin, pout, Wx, W2, b2, row_ptr, col, N);
        ushort* tmp = pin; pin = pout; pout = tmp;
    }
    reduce_kernel<<<256, 256, 0, stream>>>(pin, out, N);
}

// Round 5
// 526.766 us; speedup vs baseline: 2.4389x; 2.4389x over previous
//
#include <hip/hip_runtime.h>

#define D 64
#define F 128
#define NBMAX 256

typedef unsigned int uint;
typedef unsigned short ushort;
typedef short s16x8 __attribute__((ext_vector_type(8)));
typedef float f32x4 __attribute__((ext_vector_type(4)));

__device__ __forceinline__ float bf16lo(uint u) { return __uint_as_float(u << 16); }
__device__ __forceinline__ float bf16hi(uint u) { return __uint_as_float(u & 0xFFFF0000u); }
__device__ __forceinline__ ushort f2bf16(float f) {
    uint u = __float_as_uint(f);
    u += 0x7FFFu + ((u >> 16) & 1u);   // RNE
    return (ushort)(u >> 16);
}
__device__ __forceinline__ uint pk2bf(float lo, float hi) {
    return (uint)f2bf16(lo) | ((uint)f2bf16(hi) << 16);
}
__device__ __forceinline__ float rdlane(float v, int l) {
    return __uint_as_float(__builtin_amdgcn_readlane(__float_as_uint(v), l));
}

// ================= bucketed CSR build (N <= 65536) =================

__global__ __launch_bounds__(256) void bucket_hist(const int* __restrict__ dst,
                                                   int* __restrict__ gb, int E, int nb) {
    __shared__ int h[NBMAX];
    for (int t = threadIdx.x; t < nb; t += 256) h[t] = 0;
    __syncthreads();
    int start = blockIdx.x * 4096;
    int end   = start + 4096 < E ? start + 4096 : E;
    for (int i = start + threadIdx.x; i < end; i += 256)
        atomicAdd(&h[dst[i] >> 8], 1);
    __syncthreads();
    for (int t = threadIdx.x; t < nb; t += 256)
        if (h[t]) atomicAdd(&gb[t], h[t]);
}

__global__ void bucket_scan(const int* __restrict__ gb, int* __restrict__ gboff,
                            int* __restrict__ gcur, int nb) {
    if (threadIdx.x == 0) {
        int s = 0;
        for (int b = 0; b < nb; ++b) { gboff[b] = s; gcur[b] = s; s += gb[b]; }
        gboff[nb] = s;
    }
}

__global__ __launch_bounds__(256) void bucket_scatter(const int* __restrict__ src,
                                                      const int* __restrict__ dst,
                                                      int* __restrict__ gcur,
                                                      int* __restrict__ packed, int E, int nb) {
    __shared__ int h[NBMAX], base[NBMAX], lcur[NBMAX];
    for (int t = threadIdx.x; t < nb; t += 256) h[t] = 0;
    __syncthreads();
    int start = blockIdx.x * 4096;
    int end   = start + 4096 < E ? start + 4096 : E;
    for (int i = start + threadIdx.x; i < end; i += 256)
        atomicAdd(&h[dst[i] >> 8], 1);
    __syncthreads();
    for (int t = threadIdx.x; t < nb; t += 256) {
        base[t] = h[t] ? atomicAdd(&gcur[t], h[t]) : 0;
        lcur[t] = 0;
    }
    __syncthreads();
    for (int i = start + threadIdx.x; i < end; i += 256) {
        int d = dst[i];
        int b = d >> 8;
        int pos = base[b] + atomicAdd(&lcur[b], 1);
        packed[pos] = (src[i] << 8) | (d & 255);
    }
}

__global__ __launch_bounds__(256) void bucket_deg(const int* __restrict__ gboff,
                                                  const int* __restrict__ packed,
                                                  int* __restrict__ deg, int N) {
    __shared__ int h[NBMAX];
    int b = blockIdx.x;
    h[threadIdx.x] = 0;
    __syncthreads();
    int st = gboff[b], en = gboff[b + 1];
    for (int i = st + threadIdx.x; i < en; i += 256)
        atomicAdd(&h[packed[i] & 255], 1);
    __syncthreads();
    int node = (b << 8) + threadIdx.x;
    if (node < N) deg[node] = h[threadIdx.x];
}

__global__ __launch_bounds__(256) void bucket_fill(const int* __restrict__ gboff,
                                                   const int* __restrict__ packed,
                                                   const int* __restrict__ row_ptr,
                                                   int* __restrict__ col, int N) {
    __shared__ int lcur[NBMAX];
    int b = blockIdx.x;
    int node = (b << 8) + threadIdx.x;
    lcur[threadIdx.x] = (node < N) ? row_ptr[node] : 0;
    __syncthreads();
    int st = gboff[b], en = gboff[b + 1];
    for (int i = st + threadIdx.x; i < en; i += 256) {
        int p = packed[i];
        int pos = atomicAdd(&lcur[p & 255], 1);
        col[pos] = p >> 8;
    }
}

// ================= fallback CSR build (N > 65536) =================

__global__ void count_deg_kernel(const int* __restrict__ dst, int* __restrict__ deg, int E) {
    int i = blockIdx.x * blockDim.x + threadIdx.x;
    if (i < E) atomicAdd(&deg[dst[i]], 1);
}

__global__ void fill_kernel(const int* __restrict__ src, const int* __restrict__ dst,
                            int* __restrict__ cursor, int* __restrict__ col, int E) {
    int i = blockIdx.x * blockDim.x + threadIdx.x;
    if (i < E) {
        int d_ = dst[i];
        int pos = atomicAdd(&cursor[d_], 1);
        col[pos] = src[i];
    }
}

// ================= row_ptr scan (deg padded to multiple of 16) =================

__global__ __launch_bounds__(1024) void scan_kernel(const int* __restrict__ deg,
                                                    int* __restrict__ row_ptr, int n) {
    __shared__ int wsum[16];
    int lane = threadIdx.x & 63;
    int wid  = threadIdx.x >> 6;
    int carry = 0;
    const int CH = 4096;
    for (int base = 0; base < n; base += CH) {
        int i0 = base + (int)threadIdx.x * 4;
        int v0 = (i0     < n) ? ((deg[i0]     + 15) & ~15) : 0;
        int v1 = (i0 + 1 < n) ? ((deg[i0 + 1] + 15) & ~15) : 0;
        int v2 = (i0 + 2 < n) ? ((deg[i0 + 2] + 15) & ~15) : 0;
        int v3 = (i0 + 3 < n) ? ((deg[i0 + 3] + 15) & ~15) : 0;
        int p0 = v0, p1 = p0 + v1, p2 = p1 + v2, p3 = p2 + v3;
        int tsum = p3;
        int s = tsum;
        #pragma unroll
        for (int off = 1; off < 64; off <<= 1) {
            int t = __shfl_up(s, off);
            if (lane >= off) s += t;
        }
        if (lane == 63) wsum[wid] = s;
        __syncthreads();
        int wbase = 0, chunk_total = 0;
        #pragma unroll
        for (int w = 0; w < 16; ++w) {
            int t = wsum[w];
            chunk_total += t;
            if (w < wid) wbase += t;
        }
        __syncthreads();
        int ex = carry + wbase + (s - tsum);
        if (i0     < n) row_ptr[i0 + 1] = ex + p0;
        if (i0 + 1 < n) row_ptr[i0 + 2] = ex + p1;
        if (i0 + 2 < n) row_ptr[i0 + 3] = ex + p2;
        if (i0 + 3 < n) row_ptr[i0 + 4] = ex + p3;
        carry += chunk_total;
    }
    if (threadIdx.x == 0) row_ptr[0] = 0;
}

__global__ void pad_kernel(const int* __restrict__ row_ptr, const int* __restrict__ deg,
                           int* __restrict__ col, int N) {
    int v = blockIdx.x * blockDim.x + threadIdx.x;
    if (v < N) {
        int st = row_ptr[v] + deg[v];
        int en = row_ptr[v + 1];
        for (int k = st; k < en; ++k) col[k] = N;  // zero row
    }
}

// ================= Wx via MFMA (bf16 in, f32 acc) + fused emb1 init =================

__global__ __launch_bounds__(256) void wx_mfma_kernel(const float* __restrict__ x,
                                                      const float* __restrict__ W1,
                                                      const float* __restrict__ b1,
                                                      const float* __restrict__ b2,
                                                      float* __restrict__ Wx,
                                                      ushort* __restrict__ emb, int N) {
    int lane = threadIdx.x & 63;
    int wv = blockIdx.x * 4 + (threadIdx.x >> 6);
    int nwaves = gridDim.x * 4;
    int r16 = lane & 15;
    int kg  = lane >> 4;

    s16x8 bf[4][4];
    #pragma unroll
    for (int nt = 0; nt < 4; ++nt) {
        const float* wrow = W1 + (size_t)(nt * 16 + r16) * F;
        #pragma unroll
        for (int ks = 0; ks < 4; ++ks) {
            const float4* p = reinterpret_cast<const float4*>(wrow + ks * 32 + kg * 8);
            float4 f0 = p[0], f1 = p[1];
            union { s16x8 v; uint u[4]; } t;
            t.u[0] = pk2bf(f0.x, f0.y); t.u[1] = pk2bf(f0.z, f0.w);
            t.u[2] = pk2bf(f1.x, f1.y); t.u[3] = pk2bf(f1.z, f1.w);
            bf[nt][ks] = t.v;
        }
    }
    float b1v[4], b2v[4];
    #pragma unroll
    for (int nt = 0; nt < 4; ++nt) {
        b1v[nt] = b1[nt * 16 + r16];
        b2v[nt] = b2[nt * 16 + r16];
    }

    int ntiles = (N + 15) >> 4;
    for (int tile = wv; tile < ntiles; tile += nwaves) {
        int row0 = tile << 4;
        int arow = row0 + r16;
        if (arow >= N) arow = N - 1;
        s16x8 af[4];
        #pragma unroll
        for (int ks = 0; ks < 4; ++ks) {
            const float4* p = reinterpret_cast<const float4*>(x + (size_t)arow * F + ks * 32 + kg * 8);
            float4 f0 = p[0], f1 = p[1];
            union { s16x8 v; uint u[4]; } t;
            t.u[0] = pk2bf(f0.x, f0.y); t.u[1] = pk2bf(f0.z, f0.w);
            t.u[2] = pk2bf(f1.x, f1.y); t.u[3] = pk2bf(f1.z, f1.w);
            af[ks] = t.v;
        }
        #pragma unroll
        for (int nt = 0; nt < 4; ++nt) {
            f32x4 acc = {0.f, 0.f, 0.f, 0.f};
            #pragma unroll
            for (int ks = 0; ks < 4; ++ks)
                acc = __builtin_amdgcn_mfma_f32_16x16x32_bf16(af[ks], bf[nt][ks], acc, 0, 0, 0);
            int outd = nt * 16 + r16;
            #pragma unroll
            for (int r = 0; r < 4; ++r) {
                int node = row0 + kg * 4 + r;
                if (node < N) {
                    float wxv = acc[r] + b1v[nt];
                    Wx[(size_t)node * D + outd] = wxv;
                    float e = wxv + b2v[nt];
                    emb[(size_t)node * D + outd] = f2bf16(e > 0.f ? e : 0.f);
                }
            }
        }
    }
}

// ================= fused iteration (bf16 emb), pipelined gathers =================
// lane = 8*g + s: group g covers neighbor slots k+g, k+8+g; lane reads 16B (8 dims).

__global__ __launch_bounds__(256) void step_kernel(const ushort* __restrict__ emb_in,
                                                   ushort* __restrict__ emb_out,
                                                   const float* __restrict__ Wx,
                                                   const float* __restrict__ W2,
                                                   const float* __restrict__ b2,
                                                   const int* __restrict__ row_ptr,
                                                   const int* __restrict__ col, int N) {
    __shared__ float w2t[D][D + 1];  // w2t[k][d] = W2[d][k]; +1 pad -> conflict-free
    int t = threadIdx.x;
    #pragma unroll
    for (int i = t; i < D * D; i += 256) {
        int dd = i >> 6, kk = i & 63;
        w2t[kk][dd] = W2[i];
    }
    __syncthreads();
    int lane = t & 63, wid = t >> 6;
    float b2v = b2[lane];
    int g = lane >> 3, s = lane & 7;
    int nw = gridDim.x * 4;
    for (int v = blockIdx.x * 4 + wid; v < N; v += nw) {
        int st = row_ptr[v], en = row_ptr[v + 1];  // multiple of 16
        float a0 = 0.f, a1 = 0.f, a2 = 0.f, a3 = 0.f, a4 = 0.f, a5 = 0.f, a6 = 0.f, a7 = 0.f;
        if (st < en) {
            int u0 = col[st + g], u1 = col[st + 8 + g];
            uint4 q0 = reinterpret_cast<const uint4*>(emb_in + ((size_t)u0 << 6))[s];
            uint4 q1 = reinterpret_cast<const uint4*>(emb_in + ((size_t)u1 << 6))[s];
            int k = st + 16;
            int n0 = N, n1 = N;
            if (k < en) { n0 = col[k + g]; n1 = col[k + 8 + g]; }
            for (; k < en; k += 16) {
                uint4 p0 = reinterpret_cast<const uint4*>(emb_in + ((size_t)n0 << 6))[s];
                uint4 p1 = reinterpret_cast<const uint4*>(emb_in + ((size_t)n1 << 6))[s];
                int k2 = k + 16;
                int m0 = N, m1 = N;
                if (k2 < en) { m0 = col[k2 + g]; m1 = col[k2 + 8 + g]; }
                a0 += bf16lo(q0.x); a1 += bf16hi(q0.x);
                a2 += bf16lo(q0.y); a3 += bf16hi(q0.y);
                a4 += bf16lo(q0.z); a5 += bf16hi(q0.z);
                a6 += bf16lo(q0.w); a7 += bf16hi(q0.w);
                a0 += bf16lo(q1.x); a1 += bf16hi(q1.x);
                a2 += bf16lo(q1.y); a3 += bf16hi(q1.y);
                a4 += bf16lo(q1.z); a5 += bf16hi(q1.z);
                a6 += bf16lo(q1.w); a7 += bf16hi(q1.w);
                q0 = p0; q1 = p1; n0 = m0; n1 = m1;
            }
            a0 += bf16lo(q0.x); a1 += bf16hi(q0.x);
            a2 += bf16lo(q0.y); a3 += bf16hi(q0.y);
            a4 += bf16lo(q0.z); a5 += bf16hi(q0.z);
            a6 += bf16lo(q0.w); a7 += bf16hi(q0.w);
            a0 += bf16lo(q1.x); a1 += bf16hi(q1.x);
            a2 += bf16lo(q1.y); a3 += bf16hi(q1.y);
            a4 += bf16lo(q1.z); a5 += bf16hi(q1.z);
            a6 += bf16lo(q1.w); a7 += bf16hi(q1.w);
        }
        #pragma unroll
        for (int off = 8; off < 64; off <<= 1) {
            a0 += __shfl_xor(a0, off); a1 += __shfl_xor(a1, off);
            a2 += __shfl_xor(a2, off); a3 += __shfl_xor(a3, off);
            a4 += __shfl_xor(a4, off); a5 += __shfl_xor(a5, off);
            a6 += __shfl_xor(a6, off); a7 += __shfl_xor(a7, off);
        }
        float r = Wx[(size_t)v * D + lane] + b2v;
        #pragma unroll
        for (int kk = 0; kk < D; ++kk) {
            float av;
            switch (kk & 7) {
                case 0: av = rdlane(a0, kk >> 3); break;
                case 1: av = rdlane(a1, kk >> 3); break;
                case 2: av = rdlane(a2, kk >> 3); break;
                case 3: av = rdlane(a3, kk >> 3); break;
                case 4: av = rdlane(a4, kk >> 3); break;
                case 5: av = rdlane(a5, kk >> 3); break;
                case 6: av = rdlane(a6, kk >> 3); break;
                default: av = rdlane(a7, kk >> 3); break;
            }
            r += av * w2t[kk][lane];
        }
        emb_out[(size_t)v * D + lane] = f2bf16(r > 0.f ? r : 0.f);
    }
}

// ================= final: out[d] = sum_v emb[v][d] =================

__global__ __launch_bounds__(256) void reduce_kernel(const ushort* __restrict__ emb,
                                                     float* __restrict__ out, int N) {
    int lane = threadIdx.x & 63;
    int wid  = threadIdx.x >> 6;
    float acc = 0.f;
    int nw = gridDim.x * 4;
    for (int v = blockIdx.x * 4 + wid; v < N; v += nw)
        acc += __uint_as_float((uint)emb[(size_t)v * D + lane] << 16);
    __shared__ float red[256];
    red[threadIdx.x] = acc;
    __syncthreads();
    if (threadIdx.x < 64) {
        float sum = red[threadIdx.x] + red[threadIdx.x + 64] +
                    red[threadIdx.x + 128] + red[threadIdx.x + 192];
        atomicAdd(&out[threadIdx.x], sum);
    }
}

extern "C" void kernel_launch(void* const* d_in, const int* in_sizes, int n_in,
                              void* d_out, int out_size, void* d_ws, size_t ws_size,
                              hipStream_t stream) {
    const float* x    = (const float*)d_in[0];
    const float* W1   = (const float*)d_in[1];
    const float* b1   = (const float*)d_in[2];
    const float* W2   = (const float*)d_in[3];
    const float* b2   = (const float*)d_in[4];
    const int*   esrc = (const int*)d_in[5];
    const int*   edst = (const int*)d_in[6];
    int N = in_sizes[0] / F;
    int E = in_sizes[5];
    float* out = (float*)d_out;

    char* ws = (char*)d_ws;
    size_t off = 0;
    auto alloc = [&](size_t bytes) -> char* {
        char* p = ws + off;
        off += (bytes + 255) & ~(size_t)255;
        return p;
    };
    float*  Wx      = (float*)alloc((size_t)N * D * 4);
    ushort* embA    = (ushort*)alloc(((size_t)N + 1) * D * 2);
    ushort* embB    = (ushort*)alloc(((size_t)N + 1) * D * 2);
    int*    row_ptr = (int*)alloc(((size_t)N + 1) * 4);
    int*    deg     = (int*)alloc((size_t)N * 4);
    int*    col     = (int*)alloc(((size_t)E + 15 * (size_t)N) * 4);
    int*    packed  = (int*)alloc((size_t)E * 4);
    int*    gb      = (int*)alloc((NBMAX + 1) * 4);
    int*    gboff   = (int*)alloc((NBMAX + 1) * 4);
    int*    gcur    = (int*)alloc((NBMAX + 1) * 4);
    int*    cursor  = (int*)alloc((size_t)N * 4);  // fallback path only

    hipMemsetAsync(out, 0, (size_t)out_size * 4, stream);
    hipMemsetAsync(embA + (size_t)N * D, 0, D * 2, stream);
    hipMemsetAsync(embB + (size_t)N * D, 0, D * 2, stream);

    int nb = ((N - 1) >> 8) + 1;
    int nchunks = (E + 4095) / 4096;
    if (N <= 65536) {
        hipMemsetAsync(gb, 0, (size_t)nb * 4, stream);
        bucket_hist<<<nchunks, 256, 0, stream>>>(edst, gb, E, nb);
        bucket_scan<<<1, 64, 0, stream>>>(gb, gboff, gcur, nb);
        bucket_scatter<<<nchunks, 256, 0, stream>>>(esrc, edst, gcur, packed, E, nb);
        bucket_deg<<<nb, 256, 0, stream>>>(gboff, packed, deg, N);
        scan_kernel<<<1, 1024, 0, stream>>>(deg, row_ptr, N);
        bucket_fill<<<nb, 256, 0, stream>>>(gboff, packed, row_ptr, col, N);
    } else {
        hipMemsetAsync(deg, 0, (size_t)N * 4, stream);
        count_deg_kernel<<<(E + 255) / 256, 256, 0, stream>>>(edst, deg, E);
        scan_kernel<<<1, 1024, 0, stream>>>(deg, row_ptr, N);
        hipMemcpyAsync(cursor, row_ptr, (size_t)N * 4, hipMemcpyDeviceToDevice, stream);
        fill_kernel<<<(E + 255) / 256, 256, 0, stream>>>(esrc, edst, cursor, col, E);
    }
    pad_kernel<<<(N + 255) / 256, 256, 0, stream>>>(row_ptr, deg, col, N);

    wx_mfma_kernel<<<256, 256, 0, stream>>>(x, W1, b1, b2, Wx, embA, N);

    ushort* pin = embA;
    ushort* pout = embB;
    for (int t = 1; t < 10; ++t) {
        step_kernel<<<2048, 256, 0, stream>>>(pin, pout, Wx, W2, b2, row_ptr, col, N);
        ushort* tmp = pin; pin = pout; pout = tmp;
    }
    reduce_kernel<<<256, 256, 0, stream>>>(pin, out, N);
}